// Round 26
// baseline (208.330 us; speedup 1.0000x reference)
//
#include <hip/hip_runtime.h>
#include <cstdint>
#include <cstddef>

#define F_IN 512
#define F_HID 32
#define N_CLS 16
#define BSH 9                 // 512 nodes per bucket
#define BNODES (1 << BSH)
#define CAP 20480             // padded bucket capacity (expected 16327, sigma~128)
#define SK 16

typedef __attribute__((ext_vector_type(4))) float f32x4;
typedef __attribute__((ext_vector_type(8))) __bf16 bf16x8;

__device__ __forceinline__ short bf16s(float f) {
    unsigned u = __float_as_uint(f);
    return (short)((u + 0x7FFFu + ((u >> 16) & 1u)) >> 16);
}
__device__ __forceinline__ unsigned pack2(float a, float b) {
    return (unsigned)(unsigned short)bf16s(a) | ((unsigned)(unsigned short)bf16s(b) << 16);
}
__device__ __forceinline__ float bf_lo(unsigned p) { return __uint_as_float(p << 16); }
__device__ __forceinline__ float bf_hi(unsigned p) { return __uint_as_float(p & 0xFFFF0000u); }

// ------------- edge dtype detection (int32 vs int64) + bucket cursor init ----------
__global__ __launch_bounds__(256) void k_detect(const int* e, int* flag, int* bcur,
                                                int nbuk) {
    __shared__ int zc;
    int t = threadIdx.x;
    if (t == 0) zc = 0;
    __syncthreads();
    int z = 0;
#pragma unroll
    for (int j = 0; j < 4; ++j)
        if (e[2 * (t * 4 + j) + 1] == 0) z++;
    if (z) atomicAdd(&zc, z);
    for (int i = t; i < nbuk; i += 256) bcur[i] = i * CAP;
    __syncthreads();
    if (t == 0) *flag = (zc >= 1016) ? 1 : 0;
}

// ------------- W1 -> bf16 MFMA fragments (coalescing-friendly k-bijection) ---------
__global__ __launch_bounds__(256) void k_wcvt(const float* __restrict__ W,
                                              uint4* __restrict__ Wfrag) {
    int i = blockIdx.x * 256 + threadIdx.x;   // 0..2047
    int s = i >> 7, rem = i & 127, h = rem >> 6, l = rem & 63;
    int g = l >> 4, c = 16 * h + (l & 15);
    unsigned p[4];
#pragma unroll
    for (int q = 0; q < 4; ++q) {             // pair q covers elems j=2q, 2q+1
        int base = (q < 2) ? (4 * g + 2 * q) : (16 + 4 * g + 2 * (q - 2));
        int k0 = 32 * s + base;
        unsigned lo = (unsigned short)bf16s(W[(size_t)k0 * F_HID + c]);
        unsigned hi = (unsigned short)bf16s(W[(size_t)(k0 + 1) * F_HID + c]);
        p[q] = lo | (hi << 16);
    }
    Wfrag[i] = make_uint4(p[0], p[1], p[2], p[3]);
}

__device__ __forceinline__ int edge_get(const void* e, int is64, long long idx) {
    return is64 ? (int)((const long long*)e)[idx] : ((const int*)e)[idx];
}

// -------- FUSED: blocks [0,SB) = bucket scatter; blocks [SB,SB+NT) = gemm1 ----------
__global__ __launch_bounds__(256) void k_fused(const float* __restrict__ x,
                                               const uint4* __restrict__ Wfrag,
                                               float* __restrict__ hs1, int N,
                                               const void* edges, const int* flag,
                                               int* bcur, int* __restrict__ bucket,
                                               int E, int nbuk, int SB) {
    __shared__ uint4 wf[2048];   // 32 KB; bscatter part aliases the first 2 KB
    int t = threadIdx.x;

    if ((int)blockIdx.x < SB) {
        // ---------------- bucket scatter ----------------
        int* h = (int*)wf;
        int* sbase = h + 256;
        if (t < nbuk) h[t] = 0;
        __syncthreads();
        int is64 = *flag;
        long long base = (long long)blockIdx.x * 256 * SK;
        int ss[SK], dd[SK], rk[SK];
#pragma unroll
        for (int j = 0; j < SK; ++j) {
            long long i = base + j * 256 + t;
            if (i < E) {
                dd[j] = edge_get(edges, is64, (long long)E + i);
                ss[j] = edge_get(edges, is64, i);
                rk[j] = atomicAdd(&h[dd[j] >> BSH], 1);
            } else dd[j] = -1;
        }
        __syncthreads();
        if (t < nbuk && h[t]) sbase[t] = atomicAdd(&bcur[t], h[t]);
        __syncthreads();
#pragma unroll
        for (int j = 0; j < SK; ++j) {
            if (dd[j] >= 0) {
                int b = dd[j] >> BSH;
                int pos = sbase[b] + rk[j];
                if (pos < (b + 1) * CAP)
                    bucket[pos] = ((dd[j] & (BNODES - 1)) << 17) | ss[j];
            }
        }
    } else {
        // ---------------- gemm1 (MFMA, unscaled, coalesced pi) ----------------
#pragma unroll
        for (int j = 0; j < 8; ++j) wf[t + j * 256] = Wfrag[t + j * 256];
        __syncthreads();
        int tile = blockIdx.x - SB;
        int w = t >> 6, l = t & 63;
        int c = l & 15, g = l >> 4;
        int wrow = tile * 64 + w * 16;
        int row = wrow + c;
        if (row >= N) row = N - 1;
        const float4* xpA = (const float4*)(x + (size_t)row * F_IN + 4 * g);
        const float4* xpB = (const float4*)(x + (size_t)row * F_IN + 16 + 4 * g);

        f32x4 acc0 = {0.f, 0.f, 0.f, 0.f};
        f32x4 acc1 = {0.f, 0.f, 0.f, 0.f};

        float4 A[4], B[4];   // 4-step rolling prefetch
#pragma unroll
        for (int j = 0; j < 4; ++j) { A[j] = xpA[8 * j]; B[j] = xpB[8 * j]; }

#pragma unroll
        for (int s = 0; s < 16; ++s) {
            const int j = s & 3;
            float4 a0 = A[j], a1 = B[j];
            if (s < 12) { A[j] = xpA[8 * (s + 4)]; B[j] = xpB[8 * (s + 4)]; }
            bf16x8 av;
            av[0] = (__bf16)a0.x; av[1] = (__bf16)a0.y;
            av[2] = (__bf16)a0.z; av[3] = (__bf16)a0.w;
            av[4] = (__bf16)a1.x; av[5] = (__bf16)a1.y;
            av[6] = (__bf16)a1.z; av[7] = (__bf16)a1.w;
            bf16x8 b0 = __builtin_bit_cast(bf16x8, wf[s * 128 + l]);
            bf16x8 b1 = __builtin_bit_cast(bf16x8, wf[s * 128 + 64 + l]);
            acc0 = __builtin_amdgcn_mfma_f32_16x16x32_bf16(av, b0, acc0, 0, 0, 0);
            acc1 = __builtin_amdgcn_mfma_f32_16x16x32_bf16(av, b1, acc1, 0, 0, 0);
        }

#pragma unroll
        for (int r = 0; r < 4; ++r) {
            int ro = wrow + g * 4 + r;
            if (ro < N) {
                hs1[(size_t)ro * F_HID + c]      = acc0[r];
                hs1[(size_t)ro * F_HID + 16 + c] = acc1[r];
            }
        }
    }
}

// ------- per-bucket build: rbeg/rend + dinv + csr + hs1 scale->bf16 (hs1b) ----------
__global__ __launch_bounds__(512) void k_build(const int* __restrict__ bucket,
                                               const int* __restrict__ bcur,
                                               int* __restrict__ rbeg,
                                               int* __restrict__ rend,
                                               float* __restrict__ dinv,
                                               int* __restrict__ csr,
                                               const float* __restrict__ hs1,
                                               uint2* __restrict__ hs1b, int N) {
    __shared__ int cnt[512];
    __shared__ int wsum[8];
    __shared__ float sdinv[512];
    int b = blockIdx.x;
    int t = threadIdx.x;
    int nb0 = b << BSH;
    int beg = b * CAP, end = bcur[b];
    cnt[t] = 0;
    __syncthreads();
    for (int e = beg + t; e < end; e += 512)
        atomicAdd(&cnt[bucket[e] >> 17], 1);
    __syncthreads();
    int v = cnt[t];
    int lane = t & 63, w = t >> 6;
    int inc = v;
#pragma unroll
    for (int off = 1; off < 64; off <<= 1) {
        int u = __shfl_up(inc, off, 64);
        if (lane >= off) inc += u;
    }
    if (lane == 63) wsum[w] = inc;
    __syncthreads();
    int wo = 0;
#pragma unroll
    for (int k = 0; k < 8; ++k)
        if (k < w) wo += wsum[k];
    int excl = inc - v + wo;
    int node = nb0 + t;
    float d = rsqrtf((float)v + 1.0f);
    sdinv[t] = d;
    if (node < N) {
        rbeg[node] = beg + excl;
        rend[node] = beg + excl + v;
        dinv[node] = d;
    }
    __syncthreads();
    cnt[t] = beg + excl;  // becomes cursor
    __syncthreads();
    for (int e = beg + t; e < end; e += 512) {
        int p = bucket[e];
        int pos = atomicAdd(&cnt[p >> 17], 1);
        csr[pos] = p & 0x1FFFF;
    }
    // scale this bucket's hs1 rows by dinv and emit bf16 copy (1 line/row for gather1)
    const float4* h1 = (const float4*)hs1 + (size_t)nb0 * 8;
    uint2* hb = hs1b + (size_t)nb0 * 8;   // 8 uint2 per row (32 bf16)
    for (int j = t; j < 4096; j += 512) {
        int n2 = nb0 + (j >> 3);
        if (n2 < N) {
            float dv = sdinv[j >> 3];
            float4 vv = h1[j];
            hb[j] = make_uint2(pack2(vv.x * dv, vv.y * dv),
                               pack2(vv.z * dv, vv.w * dv));
        }
    }
}

// ------- gather1: 4 lanes/edge x uint4 (16 slots in flight) + fused gemm2 -----------
// Writes hs2b in bf16 (3.2 MB -> near L2-resident for gather2).
__global__ __launch_bounds__(256) void k_gather1(const uint4* __restrict__ hs1b4,
                                                 const int* __restrict__ csr,
                                                 const int* __restrict__ rbeg,
                                                 const int* __restrict__ rend,
                                                 const float* __restrict__ dinv,
                                                 const float* __restrict__ b1,
                                                 const float* __restrict__ W2,
                                                 unsigned* __restrict__ hs2b, int N) {
    __shared__ float w2s[32][17];
    int t = threadIdx.x;
    for (int i = t; i < 512; i += 256) w2s[i >> 4][i & 15] = W2[i];
    __syncthreads();
    int node = blockIdx.x * 4 + (t >> 6);
    if (node >= N) return;
    int lane = t & 63;
    int l = lane & 3;        // uint4 index: hidden dims 8l..8l+7
    int g = lane >> 2;       // edge slot 0..15
    int beg = rbeg[node], end = rend[node];
    float a[8];
#pragma unroll
    for (int i = 0; i < 8; ++i) a[i] = 0.f;
    int e = beg + g;
    int nsrc = (e < end) ? csr[e] : 0;
    for (; e < end; e += 16) {
        int src = nsrc;
        if (e + 16 < end) nsrc = csr[e + 16];
        uint4 q = hs1b4[(size_t)src * 4 + l];
        a[0] += bf_lo(q.x); a[1] += bf_hi(q.x);
        a[2] += bf_lo(q.y); a[3] += bf_hi(q.y);
        a[4] += bf_lo(q.z); a[5] += bf_hi(q.z);
        a[6] += bf_lo(q.w); a[7] += bf_hi(q.w);
    }
#pragma unroll
    for (int m = 4; m <= 32; m <<= 1)
#pragma unroll
        for (int i = 0; i < 8; ++i) a[i] += __shfl_xor(a[i], m, 64);
    uint4 sq = hs1b4[(size_t)node * 4 + l];
    float di = dinv[node];
    float4 bb0 = ((const float4*)b1)[2 * l];
    float4 bb1 = ((const float4*)b1)[2 * l + 1];
    float r[8];
    r[0] = fmaxf(di * (a[0] + bf_lo(sq.x)) + bb0.x, 0.f);
    r[1] = fmaxf(di * (a[1] + bf_hi(sq.x)) + bb0.y, 0.f);
    r[2] = fmaxf(di * (a[2] + bf_lo(sq.y)) + bb0.z, 0.f);
    r[3] = fmaxf(di * (a[3] + bf_hi(sq.y)) + bb0.w, 0.f);
    r[4] = fmaxf(di * (a[4] + bf_lo(sq.z)) + bb1.x, 0.f);
    r[5] = fmaxf(di * (a[5] + bf_hi(sq.z)) + bb1.y, 0.f);
    r[6] = fmaxf(di * (a[6] + bf_lo(sq.w)) + bb1.z, 0.f);
    r[7] = fmaxf(di * (a[7] + bf_hi(sq.w)) + bb1.w, 0.f);
    // gemm2: lane (g,l) -> class g over dims 8l..8l+7; reduce over l (masks 1,2)
    int k0 = 8 * l;
    float p = 0.f;
#pragma unroll
    for (int i = 0; i < 8; ++i) p += r[i] * w2s[k0 + i][g];
    p += __shfl_xor(p, 1, 64);
    p += __shfl_xor(p, 2, 64);
    p *= di;
    float po = __shfl_xor(p, 4, 64);   // class g^1's value
    if (l == 0 && (g & 1) == 0)
        hs2b[(size_t)node * 8 + (g >> 1)] = pack2(p, po);
}

// ------- gather2: 2 lanes/edge x uint4 (32 slots in flight) + log_softmax ----------
__global__ __launch_bounds__(256) void k_gather2(const uint4* __restrict__ hs2b4,
                                                 const int* __restrict__ csr,
                                                 const int* __restrict__ rbeg,
                                                 const int* __restrict__ rend,
                                                 const float* __restrict__ dinv,
                                                 const float* __restrict__ b2,
                                                 float* __restrict__ out, int N) {
    int node = blockIdx.x * 4 + (threadIdx.x >> 6);
    if (node >= N) return;
    int lane = threadIdx.x & 63;
    int l = lane & 1;        // uint4 half: classes 8l..8l+7
    int g = lane >> 1;       // edge slot 0..31
    int beg = rbeg[node], end = rend[node];
    float a[8];
#pragma unroll
    for (int i = 0; i < 8; ++i) a[i] = 0.f;
    int e = beg + g;
    int nsrc = (e < end) ? csr[e] : 0;
    for (; e < end; e += 32) {
        int src = nsrc;
        if (e + 32 < end) nsrc = csr[e + 32];
        uint4 q = hs2b4[(size_t)src * 2 + l];
        a[0] += bf_lo(q.x); a[1] += bf_hi(q.x);
        a[2] += bf_lo(q.y); a[3] += bf_hi(q.y);
        a[4] += bf_lo(q.z); a[5] += bf_hi(q.z);
        a[6] += bf_lo(q.w); a[7] += bf_hi(q.w);
    }
#pragma unroll
    for (int m = 2; m <= 32; m <<= 1)
#pragma unroll
        for (int i = 0; i < 8; ++i) a[i] += __shfl_xor(a[i], m, 64);
    if (g == 0) {
        uint4 sq = hs2b4[(size_t)node * 2 + l];
        float di = dinv[node];
        float4 bb0 = ((const float4*)b2)[2 * l];
        float4 bb1 = ((const float4*)b2)[2 * l + 1];
        float v[8];
        v[0] = di * (a[0] + bf_lo(sq.x)) + bb0.x;
        v[1] = di * (a[1] + bf_hi(sq.x)) + bb0.y;
        v[2] = di * (a[2] + bf_lo(sq.y)) + bb0.z;
        v[3] = di * (a[3] + bf_hi(sq.y)) + bb0.w;
        v[4] = di * (a[4] + bf_lo(sq.z)) + bb1.x;
        v[5] = di * (a[5] + bf_hi(sq.z)) + bb1.y;
        v[6] = di * (a[6] + bf_lo(sq.w)) + bb1.z;
        v[7] = di * (a[7] + bf_hi(sq.w)) + bb1.w;
        float m8 = v[0];
#pragma unroll
        for (int i = 1; i < 8; ++i) m8 = fmaxf(m8, v[i]);
        float m = fmaxf(m8, __shfl_xor(m8, 1, 64));
        float s8 = 0.f;
#pragma unroll
        for (int i = 0; i < 8; ++i) s8 += __expf(v[i] - m);
        float s = s8 + __shfl_xor(s8, 1, 64);
        float ls = m + __logf(s);
        float4* o = (float4*)out + (size_t)node * 4 + 2 * l;
        o[0] = make_float4(v[0] - ls, v[1] - ls, v[2] - ls, v[3] - ls);
        o[1] = make_float4(v[4] - ls, v[5] - ls, v[6] - ls, v[7] - ls);
    }
}

// ---------------- launch ----------------
extern "C" void kernel_launch(void* const* d_in, const int* in_sizes, int n_in,
                              void* d_out, int out_size, void* d_ws, size_t ws_size,
                              hipStream_t stream) {
    const float* x  = (const float*)d_in[0];
    const void* edges = d_in[1];
    const float* W1 = (const float*)d_in[2];
    const float* b1 = (const float*)d_in[3];
    const float* W2 = (const float*)d_in[4];
    const float* b2 = (const float*)d_in[5];
    float* out = (float*)d_out;

    const int N = in_sizes[0] / F_IN;   // 100000 (packing requires N < 131072)
    const int E = in_sizes[1] / 2;      // 3200000
    const int NBUK = (N + BNODES - 1) >> BSH;  // 196

    char* w = (char*)d_ws;
    size_t off = 0;
    auto take = [&](size_t bytes) {
        size_t o = off;
        off += (bytes + 15) & ~(size_t)15;
        return o;
    };
    float* hs1    = (float*)(w + take((size_t)N * F_HID * 4));
    uint2* hs1b   = (uint2*)(w + take((size_t)N * 8 * 8));    // bf16 [N][32] = 64 B/row
    unsigned* hs2b = (unsigned*)(w + take((size_t)N * 8 * 4)); // bf16 [N][16] = 32 B/row
    float* dinv   = (float*)(w + take((size_t)N * 4));
    int* rbeg     = (int*)(w + take((size_t)N * 4));
    int* rend     = (int*)(w + take((size_t)N * 4));
    int* bucket   = (int*)(w + take((size_t)NBUK * CAP * 4));
    int* csr      = (int*)(w + take((size_t)NBUK * CAP * 4));
    uint4* Wfrag  = (uint4*)(w + take(2048 * 16));
    int* bcur     = (int*)(w + take(1024));
    int* flag     = (int*)(w + take(16));

    hipLaunchKernelGGL(k_detect, dim3(1), dim3(256), 0, stream, (const int*)edges, flag, bcur, NBUK);
    hipLaunchKernelGGL(k_wcvt, dim3(8), dim3(256), 0, stream, W1, Wfrag);
    const int SB = (E + 256 * SK - 1) / (256 * SK);   // 782
    const int NT = (N + 63) / 64;                     // 1563
    hipLaunchKernelGGL(k_fused, dim3(SB + NT), dim3(256), 0, stream,
                       x, Wfrag, hs1, N, edges, flag, bcur, bucket, E, NBUK, SB);
    hipLaunchKernelGGL(k_build, dim3(NBUK), dim3(512), 0, stream, bucket, bcur, rbeg, rend, dinv, csr, hs1, hs1b, N);
    hipLaunchKernelGGL(k_gather1, dim3((N + 3) / 4), dim3(256), 0, stream,
                       (const uint4*)hs1b, csr, rbeg, rend, dinv, b1, W2, hs2b, N);
    hipLaunchKernelGGL(k_gather2, dim3((N + 3) / 4), dim3(256), 0, stream,
                       (const uint4*)hs2b, csr, rbeg, rend, dinv, b2, out, N);
}

// Round 27
// 205.382 us; speedup vs baseline: 1.0144x; 1.0144x over previous
//
#include <hip/hip_runtime.h>
#include <cstdint>
#include <cstddef>

#define F_IN 512
#define F_HID 32
#define N_CLS 16
#define BSH 9                 // 512 nodes per bucket
#define BNODES (1 << BSH)
#define CAP 20480             // padded bucket capacity (expected 16327, sigma~128)
#define SK 16

typedef __attribute__((ext_vector_type(4))) float f32x4;
typedef __attribute__((ext_vector_type(8))) __bf16 bf16x8;

__device__ __forceinline__ float4 shfl_xor_f4(float4 v, int mask) {
    v.x = __shfl_xor(v.x, mask, 64);
    v.y = __shfl_xor(v.y, mask, 64);
    v.z = __shfl_xor(v.z, mask, 64);
    v.w = __shfl_xor(v.w, mask, 64);
    return v;
}

__device__ __forceinline__ short bf16s(float f) {
    unsigned u = __float_as_uint(f);
    return (short)((u + 0x7FFFu + ((u >> 16) & 1u)) >> 16);
}
__device__ __forceinline__ unsigned pack2(float a, float b) {
    return (unsigned)(unsigned short)bf16s(a) | ((unsigned)(unsigned short)bf16s(b) << 16);
}
__device__ __forceinline__ float bf_lo(unsigned p) { return __uint_as_float(p << 16); }
__device__ __forceinline__ float bf_hi(unsigned p) { return __uint_as_float(p & 0xFFFF0000u); }

// ------------- edge dtype detection (int32 vs int64) + bucket cursor init ----------
__global__ __launch_bounds__(256) void k_detect(const int* e, int* flag, int* bcur,
                                                int nbuk) {
    __shared__ int zc;
    int t = threadIdx.x;
    if (t == 0) zc = 0;
    __syncthreads();
    int z = 0;
#pragma unroll
    for (int j = 0; j < 4; ++j)
        if (e[2 * (t * 4 + j) + 1] == 0) z++;
    if (z) atomicAdd(&zc, z);
    for (int i = t; i < nbuk; i += 256) bcur[i] = i * CAP;
    __syncthreads();
    if (t == 0) *flag = (zc >= 1016) ? 1 : 0;
}

// ------------- W1 -> bf16 MFMA fragments (coalescing-friendly k-bijection) ---------
__global__ __launch_bounds__(256) void k_wcvt(const float* __restrict__ W,
                                              uint4* __restrict__ Wfrag) {
    int i = blockIdx.x * 256 + threadIdx.x;   // 0..2047
    int s = i >> 7, rem = i & 127, h = rem >> 6, l = rem & 63;
    int g = l >> 4, c = 16 * h + (l & 15);
    unsigned p[4];
#pragma unroll
    for (int q = 0; q < 4; ++q) {             // pair q covers elems j=2q, 2q+1
        int base = (q < 2) ? (4 * g + 2 * q) : (16 + 4 * g + 2 * (q - 2));
        int k0 = 32 * s + base;
        unsigned lo = (unsigned short)bf16s(W[(size_t)k0 * F_HID + c]);
        unsigned hi = (unsigned short)bf16s(W[(size_t)(k0 + 1) * F_HID + c]);
        p[q] = lo | (hi << 16);
    }
    Wfrag[i] = make_uint4(p[0], p[1], p[2], p[3]);
}

__device__ __forceinline__ int edge_get(const void* e, int is64, long long idx) {
    return is64 ? (int)((const long long*)e)[idx] : ((const int*)e)[idx];
}

// -------- FUSED: blocks [0,SB) = bucket scatter; blocks [SB,SB+NT) = gemm1 ----------
__global__ __launch_bounds__(256) void k_fused(const float* __restrict__ x,
                                               const uint4* __restrict__ Wfrag,
                                               float* __restrict__ hs1, int N,
                                               const void* edges, const int* flag,
                                               int* bcur, int* __restrict__ bucket,
                                               int E, int nbuk, int SB) {
    __shared__ uint4 wf[2048];   // 32 KB; bscatter part aliases the first 2 KB
    int t = threadIdx.x;

    if ((int)blockIdx.x < SB) {
        // ---------------- bucket scatter ----------------
        int* h = (int*)wf;
        int* sbase = h + 256;
        if (t < nbuk) h[t] = 0;
        __syncthreads();
        int is64 = *flag;
        long long base = (long long)blockIdx.x * 256 * SK;
        int ss[SK], dd[SK], rk[SK];
#pragma unroll
        for (int j = 0; j < SK; ++j) {
            long long i = base + j * 256 + t;
            if (i < E) {
                dd[j] = edge_get(edges, is64, (long long)E + i);
                ss[j] = edge_get(edges, is64, i);
                rk[j] = atomicAdd(&h[dd[j] >> BSH], 1);
            } else dd[j] = -1;
        }
        __syncthreads();
        if (t < nbuk && h[t]) sbase[t] = atomicAdd(&bcur[t], h[t]);
        __syncthreads();
#pragma unroll
        for (int j = 0; j < SK; ++j) {
            if (dd[j] >= 0) {
                int b = dd[j] >> BSH;
                int pos = sbase[b] + rk[j];
                if (pos < (b + 1) * CAP)
                    bucket[pos] = ((dd[j] & (BNODES - 1)) << 17) | ss[j];
            }
        }
    } else {
        // ---------------- gemm1 (MFMA, unscaled, coalesced pi) ----------------
#pragma unroll
        for (int j = 0; j < 8; ++j) wf[t + j * 256] = Wfrag[t + j * 256];
        __syncthreads();
        int tile = blockIdx.x - SB;
        int w = t >> 6, l = t & 63;
        int c = l & 15, g = l >> 4;
        int wrow = tile * 64 + w * 16;
        int row = wrow + c;
        if (row >= N) row = N - 1;
        const float4* xpA = (const float4*)(x + (size_t)row * F_IN + 4 * g);
        const float4* xpB = (const float4*)(x + (size_t)row * F_IN + 16 + 4 * g);

        f32x4 acc0 = {0.f, 0.f, 0.f, 0.f};
        f32x4 acc1 = {0.f, 0.f, 0.f, 0.f};

        float4 A[4], B[4];   // 4-step rolling prefetch
#pragma unroll
        for (int j = 0; j < 4; ++j) { A[j] = xpA[8 * j]; B[j] = xpB[8 * j]; }

#pragma unroll
        for (int s = 0; s < 16; ++s) {
            const int j = s & 3;
            float4 a0 = A[j], a1 = B[j];
            if (s < 12) { A[j] = xpA[8 * (s + 4)]; B[j] = xpB[8 * (s + 4)]; }
            bf16x8 av;
            av[0] = (__bf16)a0.x; av[1] = (__bf16)a0.y;
            av[2] = (__bf16)a0.z; av[3] = (__bf16)a0.w;
            av[4] = (__bf16)a1.x; av[5] = (__bf16)a1.y;
            av[6] = (__bf16)a1.z; av[7] = (__bf16)a1.w;
            bf16x8 b0 = __builtin_bit_cast(bf16x8, wf[s * 128 + l]);
            bf16x8 b1 = __builtin_bit_cast(bf16x8, wf[s * 128 + 64 + l]);
            acc0 = __builtin_amdgcn_mfma_f32_16x16x32_bf16(av, b0, acc0, 0, 0, 0);
            acc1 = __builtin_amdgcn_mfma_f32_16x16x32_bf16(av, b1, acc1, 0, 0, 0);
        }

#pragma unroll
        for (int r = 0; r < 4; ++r) {
            int ro = wrow + g * 4 + r;
            if (ro < N) {
                hs1[(size_t)ro * F_HID + c]      = acc0[r];
                hs1[(size_t)ro * F_HID + 16 + c] = acc1[r];
            }
        }
    }
}

// ------- per-bucket build: rbeg/rend + dinv + csr + hs1 scale->bf16 (hs1b) ----------
__global__ __launch_bounds__(512) void k_build(const int* __restrict__ bucket,
                                               const int* __restrict__ bcur,
                                               int* __restrict__ rbeg,
                                               int* __restrict__ rend,
                                               float* __restrict__ dinv,
                                               int* __restrict__ csr,
                                               const float* __restrict__ hs1,
                                               uint2* __restrict__ hs1b, int N) {
    __shared__ int cnt[512];
    __shared__ int wsum[8];
    __shared__ float sdinv[512];
    int b = blockIdx.x;
    int t = threadIdx.x;
    int nb0 = b << BSH;
    int beg = b * CAP, end = bcur[b];
    cnt[t] = 0;
    __syncthreads();
    for (int e = beg + t; e < end; e += 512)
        atomicAdd(&cnt[bucket[e] >> 17], 1);
    __syncthreads();
    int v = cnt[t];
    int lane = t & 63, w = t >> 6;
    int inc = v;
#pragma unroll
    for (int off = 1; off < 64; off <<= 1) {
        int u = __shfl_up(inc, off, 64);
        if (lane >= off) inc += u;
    }
    if (lane == 63) wsum[w] = inc;
    __syncthreads();
    int wo = 0;
#pragma unroll
    for (int k = 0; k < 8; ++k)
        if (k < w) wo += wsum[k];
    int excl = inc - v + wo;
    int node = nb0 + t;
    float d = rsqrtf((float)v + 1.0f);
    sdinv[t] = d;
    if (node < N) {
        rbeg[node] = beg + excl;
        rend[node] = beg + excl + v;
        dinv[node] = d;
    }
    __syncthreads();
    cnt[t] = beg + excl;  // becomes cursor
    __syncthreads();
    for (int e = beg + t; e < end; e += 512) {
        int p = bucket[e];
        int pos = atomicAdd(&cnt[p >> 17], 1);
        csr[pos] = p & 0x1FFFF;
    }
    // scale this bucket's hs1 rows by dinv and emit bf16 copy (1 line/row for gather1)
    const float4* h1 = (const float4*)hs1 + (size_t)nb0 * 8;
    uint2* hb = hs1b + (size_t)nb0 * 8;   // 8 uint2 per row (32 bf16)
    for (int j = t; j < 4096; j += 512) {
        int n2 = nb0 + (j >> 3);
        if (n2 < N) {
            float dv = sdinv[j >> 3];
            float4 vv = h1[j];
            hb[j] = make_uint2(pack2(vv.x * dv, vv.y * dv),
                               pack2(vv.z * dv, vv.w * dv));
        }
    }
}

// ---- gather1 (R25 structure) + fused gemm2 -> bf16 hs2b (3.2 MB, L2-resident) ------
__global__ __launch_bounds__(256) void k_gather1(const uint2* __restrict__ hs1b,
                                                 const int* __restrict__ csr,
                                                 const int* __restrict__ rbeg,
                                                 const int* __restrict__ rend,
                                                 const float* __restrict__ dinv,
                                                 const float* __restrict__ b1,
                                                 const float* __restrict__ W2,
                                                 unsigned* __restrict__ hs2b, int N) {
    __shared__ float w2s[32][17];
    int t = threadIdx.x;
    for (int i = t; i < 512; i += 256) w2s[i >> 4][i & 15] = W2[i];
    __syncthreads();
    int node = blockIdx.x * 4 + (t >> 6);
    if (node >= N) return;
    int lane = t & 63;
    int g = lane >> 3, l = lane & 7;
    int beg = rbeg[node], end = rend[node];
    float4 a = make_float4(0.f, 0.f, 0.f, 0.f);
    int e = beg + g;
    int nsrc = (e < end) ? csr[e] : 0;
    for (; e < end; e += 8) {
        int src = nsrc;
        if (e + 8 < end) nsrc = csr[e + 8];
        uint2 q = hs1b[(size_t)src * 8 + l];
        a.x += bf_lo(q.x); a.y += bf_hi(q.x);
        a.z += bf_lo(q.y); a.w += bf_hi(q.y);
    }
    float4 u;
    u = shfl_xor_f4(a, 8);  a.x += u.x; a.y += u.y; a.z += u.z; a.w += u.w;
    u = shfl_xor_f4(a, 16); a.x += u.x; a.y += u.y; a.z += u.z; a.w += u.w;
    u = shfl_xor_f4(a, 32); a.x += u.x; a.y += u.y; a.z += u.z; a.w += u.w;
    uint2 sq = hs1b[(size_t)node * 8 + l];
    float di = dinv[node];
    float4 bb = ((const float4*)b1)[l];
    float4 r;
    r.x = fmaxf(di * (a.x + bf_lo(sq.x)) + bb.x, 0.f);
    r.y = fmaxf(di * (a.y + bf_hi(sq.x)) + bb.y, 0.f);
    r.z = fmaxf(di * (a.z + bf_lo(sq.y)) + bb.z, 0.f);
    r.w = fmaxf(di * (a.w + bf_hi(sq.y)) + bb.w, 0.f);
    int k0 = 4 * l, c0 = 2 * g;
    float p0 = r.x * w2s[k0][c0]     + r.y * w2s[k0 + 1][c0]
             + r.z * w2s[k0 + 2][c0] + r.w * w2s[k0 + 3][c0];
    float p1 = r.x * w2s[k0][c0 + 1]     + r.y * w2s[k0 + 1][c0 + 1]
             + r.z * w2s[k0 + 2][c0 + 1] + r.w * w2s[k0 + 3][c0 + 1];
    p0 += __shfl_xor(p0, 1, 64); p1 += __shfl_xor(p1, 1, 64);
    p0 += __shfl_xor(p0, 2, 64); p1 += __shfl_xor(p1, 2, 64);
    p0 += __shfl_xor(p0, 4, 64); p1 += __shfl_xor(p1, 4, 64);
    if (l == 0)
        hs2b[(size_t)node * 8 + g] = pack2(p0 * di, p1 * di);   // classes 2g,2g+1
}

// ------- gather2: 2 lanes/edge x uint4 (32 slots in flight) + log_softmax ----------
__global__ __launch_bounds__(256) void k_gather2(const uint4* __restrict__ hs2b4,
                                                 const int* __restrict__ csr,
                                                 const int* __restrict__ rbeg,
                                                 const int* __restrict__ rend,
                                                 const float* __restrict__ dinv,
                                                 const float* __restrict__ b2,
                                                 float* __restrict__ out, int N) {
    int node = blockIdx.x * 4 + (threadIdx.x >> 6);
    if (node >= N) return;
    int lane = threadIdx.x & 63;
    int l = lane & 1;        // uint4 half: classes 8l..8l+7
    int g = lane >> 1;       // edge slot 0..31
    int beg = rbeg[node], end = rend[node];
    float a[8];
#pragma unroll
    for (int i = 0; i < 8; ++i) a[i] = 0.f;
    int e = beg + g;
    int nsrc = (e < end) ? csr[e] : 0;
    for (; e < end; e += 32) {
        int src = nsrc;
        if (e + 32 < end) nsrc = csr[e + 32];
        uint4 q = hs2b4[(size_t)src * 2 + l];
        a[0] += bf_lo(q.x); a[1] += bf_hi(q.x);
        a[2] += bf_lo(q.y); a[3] += bf_hi(q.y);
        a[4] += bf_lo(q.z); a[5] += bf_hi(q.z);
        a[6] += bf_lo(q.w); a[7] += bf_hi(q.w);
    }
#pragma unroll
    for (int m = 2; m <= 32; m <<= 1)
#pragma unroll
        for (int i = 0; i < 8; ++i) a[i] += __shfl_xor(a[i], m, 64);
    if (g == 0) {
        uint4 sq = hs2b4[(size_t)node * 2 + l];
        float di = dinv[node];
        float4 bb0 = ((const float4*)b2)[2 * l];
        float4 bb1 = ((const float4*)b2)[2 * l + 1];
        float v[8];
        v[0] = di * (a[0] + bf_lo(sq.x)) + bb0.x;
        v[1] = di * (a[1] + bf_hi(sq.x)) + bb0.y;
        v[2] = di * (a[2] + bf_lo(sq.y)) + bb0.z;
        v[3] = di * (a[3] + bf_hi(sq.y)) + bb0.w;
        v[4] = di * (a[4] + bf_lo(sq.z)) + bb1.x;
        v[5] = di * (a[5] + bf_hi(sq.z)) + bb1.y;
        v[6] = di * (a[6] + bf_lo(sq.w)) + bb1.z;
        v[7] = di * (a[7] + bf_hi(sq.w)) + bb1.w;
        float m8 = v[0];
#pragma unroll
        for (int i = 1; i < 8; ++i) m8 = fmaxf(m8, v[i]);
        float m = fmaxf(m8, __shfl_xor(m8, 1, 64));
        float s8 = 0.f;
#pragma unroll
        for (int i = 0; i < 8; ++i) s8 += __expf(v[i] - m);
        float s = s8 + __shfl_xor(s8, 1, 64);
        float ls = m + __logf(s);
        float4* o = (float4*)out + (size_t)node * 4 + 2 * l;
        o[0] = make_float4(v[0] - ls, v[1] - ls, v[2] - ls, v[3] - ls);
        o[1] = make_float4(v[4] - ls, v[5] - ls, v[6] - ls, v[7] - ls);
    }
}

// ---------------- launch ----------------
extern "C" void kernel_launch(void* const* d_in, const int* in_sizes, int n_in,
                              void* d_out, int out_size, void* d_ws, size_t ws_size,
                              hipStream_t stream) {
    const float* x  = (const float*)d_in[0];
    const void* edges = d_in[1];
    const float* W1 = (const float*)d_in[2];
    const float* b1 = (const float*)d_in[3];
    const float* W2 = (const float*)d_in[4];
    const float* b2 = (const float*)d_in[5];
    float* out = (float*)d_out;

    const int N = in_sizes[0] / F_IN;   // 100000 (packing requires N < 131072)
    const int E = in_sizes[1] / 2;      // 3200000
    const int NBUK = (N + BNODES - 1) >> BSH;  // 196

    char* w = (char*)d_ws;
    size_t off = 0;
    auto take = [&](size_t bytes) {
        size_t o = off;
        off += (bytes + 15) & ~(size_t)15;
        return o;
    };
    float* hs1    = (float*)(w + take((size_t)N * F_HID * 4));
    uint2* hs1b   = (uint2*)(w + take((size_t)N * 8 * 8));     // bf16 [N][32] = 64 B/row
    unsigned* hs2b = (unsigned*)(w + take((size_t)N * 8 * 4)); // bf16 [N][16] = 32 B/row
    float* dinv   = (float*)(w + take((size_t)N * 4));
    int* rbeg     = (int*)(w + take((size_t)N * 4));
    int* rend     = (int*)(w + take((size_t)N * 4));
    int* bucket   = (int*)(w + take((size_t)NBUK * CAP * 4));
    int* csr      = (int*)(w + take((size_t)NBUK * CAP * 4));
    uint4* Wfrag  = (uint4*)(w + take(2048 * 16));
    int* bcur     = (int*)(w + take(1024));
    int* flag     = (int*)(w + take(16));

    hipLaunchKernelGGL(k_detect, dim3(1), dim3(256), 0, stream, (const int*)edges, flag, bcur, NBUK);
    hipLaunchKernelGGL(k_wcvt, dim3(8), dim3(256), 0, stream, W1, Wfrag);
    const int SB = (E + 256 * SK - 1) / (256 * SK);   // 782
    const int NT = (N + 63) / 64;                     // 1563
    hipLaunchKernelGGL(k_fused, dim3(SB + NT), dim3(256), 0, stream,
                       x, Wfrag, hs1, N, edges, flag, bcur, bucket, E, NBUK, SB);
    hipLaunchKernelGGL(k_build, dim3(NBUK), dim3(512), 0, stream, bucket, bcur, rbeg, rend, dinv, csr, hs1, hs1b, N);
    hipLaunchKernelGGL(k_gather1, dim3((N + 3) / 4), dim3(256), 0, stream,
                       hs1b, csr, rbeg, rend, dinv, b1, W2, hs2b, N);
    hipLaunchKernelGGL(k_gather2, dim3((N + 3) / 4), dim3(256), 0, stream,
                       (const uint4*)hs2b, csr, rbeg, rend, dinv, b2, out, N);
}